// Round 7
// baseline (385.595 us; speedup 1.0000x reference)
//
#include <hip/hip_runtime.h>
#include <hip/hip_bf16.h>
#include <stdint.h>

// Problem constants (from setup_inputs): B=8192, D_in=1024, H=2048
#define B_DIM 8192
#define D_IN  1024
#define H_DIM 2048
#define K_DIM (D_IN + H_DIM)   // 3072: A = [x | u], Wc = [win | wr]

#define CV_CONST  (1.0f - 1.0f/150.0f)   // (1-ALPHA_V)
#define CUV_CONST (10.0f/150.0f)         // ALPHA_V*M
#define CU_CONST  0.9f                   // (1-ALPHA_U)
#define AU_CONST  0.1f                   // ALPHA_U

typedef __attribute__((ext_vector_type(8))) short short8;   // 8 bf16 = 4 VGPRs
typedef __attribute__((ext_vector_type(4))) float floatx4;

__device__ __forceinline__ unsigned short f2bf(float f) {
    union { float f; unsigned u; } x; x.f = f;
    unsigned r = x.u + 0x7fffu + ((x.u >> 16) & 1u);
    return (unsigned short)(r >> 16);
}

// ---------------------------------------------------------------------------
// Single fused pack: x,u -> Abf[8192][3072]; win,wr -> Wbf[2048][3072], bf16 RNE.
// ---------------------------------------------------------------------------
#define N4_X   ((B_DIM * D_IN)  / 4)   // 2097152
#define N4_U   ((B_DIM * H_DIM) / 4)   // 4194304
#define N4_WIN ((H_DIM * D_IN)  / 4)   //  524288
#define N4_WR  ((H_DIM * H_DIM) / 4)   // 1048576
#define N4_TOT (N4_X + N4_U + N4_WIN + N4_WR)   // 7864320 (= 30720 * 256)

__global__ __launch_bounds__(256)
void pack_all(const float4* __restrict__ x, const float4* __restrict__ u,
              const float4* __restrict__ win, const float4* __restrict__ wr,
              unsigned short* __restrict__ Abf, unsigned short* __restrict__ Wbf) {
    int i = blockIdx.x * 256 + threadIdx.x;
    const float4* src; unsigned short* dst; int shift, mask, coloff;
    if (i < N4_X)                    { src = x;   dst = Abf; shift = 10; mask = 1023; coloff = 0;    }
    else if (i < N4_X + N4_U)        { i -= N4_X; src = u;   dst = Abf; shift = 11; mask = 2047; coloff = D_IN; }
    else if (i < N4_X + N4_U + N4_WIN){ i -= N4_X + N4_U; src = win; dst = Wbf; shift = 10; mask = 1023; coloff = 0; }
    else                             { i -= N4_X + N4_U + N4_WIN; src = wr; dst = Wbf; shift = 11; mask = 2047; coloff = D_IN; }
    int idx = i << 2;
    int r = idx >> shift;
    int c = idx & mask;
    float4 f = src[i];
    ushort4 o;
    o.x = f2bf(f.x); o.y = f2bf(f.y); o.z = f2bf(f.z); o.w = f2bf(f.w);
    *(ushort4*)(dst + (size_t)r * K_DIM + coloff + c) = o;
}

// ---------------------------------------------------------------------------
// R7 = R2 champion skeleton (4-phase proof-ahead, 147.5 µs) + u/v L3-prefetch,
// FIXED: the R6 touch used global_load_dword into a dead VGPR — the delayed
// hardware writeback clobbered whatever the register allocator later put in
// that physical register (absmax 0.4). Now the touch is a
// global_load_lds(size=4) into a 2 KiB LDS dump region: NO register
// writeback exists, and the LDS write lands in scratch nothing reads.
// During the first 16 K-tiles each wave issues one touch per tile (64 lanes x
// one 64B line) -> the block's full 512 KB u/v epilogue slice is pulled
// HBM->L3 while the HBM bus is otherwise idle (A/Wc staging is L2/L3-hit).
// vmcnt bookkeeping (touch shares the in-order VMEM queue):
//   touch-tiles: P0 VMCNT(5) proves Bhi(t)  (newer: Ahi2+touch+Alo2 = 5)
//                P1 VMCNT(5) proves Ahi(t)  (newer: touch+Alo2+Blo2 = 5)
//                P3 VMCNT(4) proves touch+Alo+Blo (leaves Bhi2+Ahi2)
//   plain tiles: R2's exact 4/4/4 constants.
// ---------------------------------------------------------------------------
#define GLOAD_LDS16(gp, lp)                                                          \
    __builtin_amdgcn_global_load_lds(                                                \
        (const __attribute__((address_space(1))) unsigned int*)(gp),                 \
        (__attribute__((address_space(3))) unsigned int*)(lp), 16, 0, 0)

// 4-byte touch into LDS dump: no VGPR destination, shares the vmcnt queue.
#define GLOAD_LDS4(gp, lp)                                                           \
    __builtin_amdgcn_global_load_lds(                                                \
        (const __attribute__((address_space(1))) unsigned int*)(gp),                 \
        (__attribute__((address_space(3))) unsigned int*)(lp), 4, 0, 0)

#define VMCNT(n)  asm volatile("s_waitcnt vmcnt(" #n ")" ::: "memory")
#define LGKM0     asm volatile("s_waitcnt lgkmcnt(0)" ::: "memory")
#define SCHEDB    __builtin_amdgcn_sched_barrier(0)
#define BAR       __builtin_amdgcn_s_barrier()
#define PRIO1     __builtin_amdgcn_s_setprio(1)
#define PRIO0     __builtin_amdgcn_s_setprio(0)

#define NT (K_DIM / 64)        // 48 K-tiles

// LDS: 2 buffers x 64 KiB + 2 KiB touch-dump. Unit offsets within a buffer:
//   A-lo (i-frags 0..3 of both M halves) : 0
//   B-lo (j-frags 0..1 of all wc)        : 16384
//   B-hi (j-frags 2..3 of all wc)        : 32768
//   A-hi (i-frags 4..7 of both M halves) : 49152
// Each unit = 16 slots x 1024 B; slot = one wave-fragment (lane -> lane*16B).
#define ALO 0
#define BLO 16384
#define BHI 32768
#define AHI 49152
#define DUMP 131072            // 2 KiB scratch for prefetch touches (256 B/wave)

// Epilogue scratch (aliases K-loop LDS after final sync)
#define ES_STRIDE 68
#define ES_REGION (16 * ES_STRIDE)          // 1088 floats per region

__global__ __launch_bounds__(512, 2)
void gemm_fused(const unsigned short* __restrict__ A,   // [8192][3072] bf16
                const unsigned short* __restrict__ Wc,  // [2048][3072] bf16
                const float* __restrict__ u_in,         // [8192][2048]
                const float* __restrict__ v_in,         // [8192][2048]
                const float* __restrict__ bias,         // [2048]
                float* __restrict__ out)                // [u_new | v_new]
{
    __shared__ __align__(16) unsigned char smem[133120];   // 130 KiB

    const int tid  = threadIdx.x;
    const int wave = tid >> 6;       // 0..7
    const int lane = tid & 63;
    const int wrh  = wave >> 2;      // 0..1 : M half (128 rows)
    const int wc   = wave & 3;       // 0..3 : N quarter (64 cols)

    // XCD-chunked bijective swizzle (256 blocks, 256 % 8 == 0)
    const int bid   = blockIdx.x;
    const int wid   = ((bid & 7) << 5) | (bid >> 3);
    const int tileM = (wid >> 3) << 8;     // 0..31 * 256
    const int tileN = (wid & 7)  << 8;     // 0..7  * 256

    const int frow = lane & 15;
    const int g    = lane >> 4;

    // Staging source pointers: thread (wave,lane) feeds slot (r*8+wave), lane l.
    const unsigned short* Ag = A  + (size_t)(tileM + (wave >> 1) * 16 + frow) * K_DIM
                                  + (wave & 1) * 32 + g * 8;
    const unsigned short* Bg = Wc + (size_t)(tileN + (wave >> 2) * 64 + ((wave >> 1) & 1) * 16 + frow) * K_DIM
                                  + (wave & 1) * 32 + g * 8;
    const size_t R128 = (size_t)128 * K_DIM;
    const size_t R64  = (size_t) 64 * K_DIM;
    const size_t R32  = (size_t) 32 * K_DIM;

    const int w1024 = wave << 10;

    // ds_read byte bases (within a buffer): A frag (i,s) -> slot wrh*8 + i*2 + s;
    //                                       B frag (j,s) -> slot wc*4 + j*2 + s.
    const int aRd = (wrh << 13) + (lane << 4);
    const int bRd = (wc  << 12) + (lane << 4);

    // Touch pointers: lane touches one 64B line; per tile a wave covers 32 rows
    // band: row = tileM + wave*4 + (lane>>4) + t*32, col = (lane&15)*16 floats.
    // 8 u-tiles + 8 v-tiles cover the block's full 256x256 u and v slices.
    const size_t trow = (size_t)(tileM + wave * 4 + (lane >> 4)) * H_DIM
                      + tileN + (lane & 15) * 16;
    const float* tpu = u_in + trow;
    const float* tpv = v_in + trow;
    unsigned char* dump = smem + DUMP + (wave << 8);   // 256 B per wave

    // ---- prologue: stage tile 0 into buffer 0 (order: Alo, Blo, Bhi, Ahi)
    GLOAD_LDS16(Ag,               smem + ALO + w1024);
    GLOAD_LDS16(Ag + R128,        smem + ALO + 8192 + w1024);
    GLOAD_LDS16(Bg,               smem + BLO + w1024);
    GLOAD_LDS16(Bg + R128,        smem + BLO + 8192 + w1024);
    GLOAD_LDS16(Bg + R32,         smem + BHI + w1024);
    GLOAD_LDS16(Bg + R32 + R128,  smem + BHI + 8192 + w1024);
    GLOAD_LDS16(Ag + R64,         smem + AHI + w1024);
    GLOAD_LDS16(Ag + R64 + R128,  smem + AHI + 8192 + w1024);

    // Prove 0.Alo + 0.Blo landed (all waves), then barrier + fence.
    VMCNT(4);
    BAR;
    LGKM0;

    floatx4 acc[8][4] = {};
    short8 Ar[4][2], Bl[2][2], Bh[2][2];

#define RD_A(cb, unit, i2s) (*(const short8*)(smem + (cb) + (unit) + aRd + (i2s) * 1024))
#define RD_B(cb, unit, j2s) (*(const short8*)(smem + (cb) + (unit) + bRd + (j2s) * 1024))

// One K-tile, R2 skeleton. TCH = optional touch statement (issued first in P0);
// NA/NB = P0/P1 vmcnt counts (4/4 plain, 5/5 with touch in flight).
#define K_TILE(T, TCH, NA, NB)                                                       \
    {                                                                                \
        const int cb = ((T) & 1) << 16;                                              \
        const int nb = cb ^ 65536;                                                   \
        const size_t kk = (size_t)((T) + 1) * 64;                                    \
        /* P0: touch; stage next A-lo; read cb.Alo+cb.Blo (proven @prev P3);  */     \
        /*     prove cb.Bhi for P1.                                           */     \
        TCH                                                                          \
        GLOAD_LDS16(Ag + kk,        smem + nb + ALO + w1024);                        \
        GLOAD_LDS16(Ag + kk + R128, smem + nb + ALO + 8192 + w1024);                 \
        _Pragma("unroll")                                                            \
        for (int i = 0; i < 4; ++i) { Ar[i][0] = RD_A(cb, ALO, i*2); Ar[i][1] = RD_A(cb, ALO, i*2+1); } \
        _Pragma("unroll")                                                            \
        for (int j = 0; j < 2; ++j) { Bl[j][0] = RD_B(cb, BLO, j*2); Bl[j][1] = RD_B(cb, BLO, j*2+1); } \
        VMCNT(NA); BAR; LGKM0; SCHEDB;                                               \
        PRIO1;                                                                       \
        _Pragma("unroll")                                                            \
        for (int i = 0; i < 4; ++i)                                                  \
            _Pragma("unroll")                                                        \
            for (int j = 0; j < 2; ++j) {                                            \
                acc[i][j] = __builtin_amdgcn_mfma_f32_16x16x32_bf16(Ar[i][0], Bl[j][0], acc[i][j], 0, 0, 0); \
                acc[i][j] = __builtin_amdgcn_mfma_f32_16x16x32_bf16(Ar[i][1], Bl[j][1], acc[i][j], 0, 0, 0); \
            }                                                                        \
        PRIO0; SCHEDB; BAR;                                                          \
        /* P1: stage next B-lo; read cb.Bhi; prove cb.Ahi for P2. */                 \
        GLOAD_LDS16(Bg + kk,        smem + nb + BLO + w1024);                        \
        GLOAD_LDS16(Bg + kk + R128, smem + nb + BLO + 8192 + w1024);                 \
        _Pragma("unroll")                                                            \
        for (int j = 0; j < 2; ++j) { Bh[j][0] = RD_B(cb, BHI, j*2); Bh[j][1] = RD_B(cb, BHI, j*2+1); } \
        VMCNT(NB); BAR; LGKM0; SCHEDB;                                               \
        PRIO1;                                                                       \
        _Pragma("unroll")                                                            \
        for (int i = 0; i < 4; ++i)                                                  \
            _Pragma("unroll")                                                        \
            for (int j = 0; j < 2; ++j) {                                            \
                acc[i][2+j] = __builtin_amdgcn_mfma_f32_16x16x32_bf16(Ar[i][0], Bh[j][0], acc[i][2+j], 0, 0, 0); \
                acc[i][2+j] = __builtin_amdgcn_mfma_f32_16x16x32_bf16(Ar[i][1], Bh[j][1], acc[i][2+j], 0, 0, 0); \
            }                                                                        \
        PRIO0; SCHEDB; BAR;                                                          \
        /* P2: stage next B-hi; read cb.Ahi (overwrites Ar); nothing to prove. */    \
        GLOAD_LDS16(Bg + kk + R32,        smem + nb + BHI + w1024);                  \
        GLOAD_LDS16(Bg + kk + R32 + R128, smem + nb + BHI + 8192 + w1024);           \
        _Pragma("unroll")                                                            \
        for (int i = 0; i < 4; ++i) { Ar[i][0] = RD_A(cb, AHI, i*2); Ar[i][1] = RD_A(cb, AHI, i*2+1); } \
        BAR; LGKM0; SCHEDB;                                                          \
        PRIO1;                                                                       \
        _Pragma("unroll")                                                            \
        for (int i = 0; i < 4; ++i)                                                  \
            _Pragma("unroll")                                                        \
            for (int j = 0; j < 2; ++j) {                                            \
                acc[4+i][2+j] = __builtin_amdgcn_mfma_f32_16x16x32_bf16(Ar[i][0], Bh[j][0], acc[4+i][2+j], 0, 0, 0); \
                acc[4+i][2+j] = __builtin_amdgcn_mfma_f32_16x16x32_bf16(Ar[i][1], Bh[j][1], acc[4+i][2+j], 0, 0, 0); \
            }                                                                        \
        PRIO0; SCHEDB; BAR;                                                          \
        /* P3: stage next A-hi; prove (t+1).Alo+(t+1).Blo (touch retires too). */    \
        GLOAD_LDS16(Ag + kk + R64,        smem + nb + AHI + w1024);                  \
        GLOAD_LDS16(Ag + kk + R64 + R128, smem + nb + AHI + 8192 + w1024);           \
        VMCNT(4); BAR; LGKM0; SCHEDB;                                                \
        PRIO1;                                                                       \
        _Pragma("unroll")                                                            \
        for (int i = 0; i < 4; ++i)                                                  \
            _Pragma("unroll")                                                        \
            for (int j = 0; j < 2; ++j) {                                            \
                acc[4+i][j] = __builtin_amdgcn_mfma_f32_16x16x32_bf16(Ar[i][0], Bl[j][0], acc[4+i][j], 0, 0, 0); \
                acc[4+i][j] = __builtin_amdgcn_mfma_f32_16x16x32_bf16(Ar[i][1], Bl[j][1], acc[4+i][j], 0, 0, 0); \
            }                                                                        \
        PRIO0; SCHEDB; BAR;                                                          \
    }

#define TOUCH_U { GLOAD_LDS4(tpu, dump); tpu += 32 * (size_t)H_DIM; }
#define TOUCH_V { GLOAD_LDS4(tpv, dump); tpv += 32 * (size_t)H_DIM; }
#define TOUCH_NONE

    // tiles 0..7: touch u slice; 8..15: touch v slice; 16..46: plain
    for (int t = 0; t < 8; ++t)   K_TILE(t, TOUCH_U, 5, 5)
    for (int t = 8; t < 16; ++t)  K_TILE(t, TOUCH_V, 5, 5)
    for (int t = 16; t < NT - 1; ++t) K_TILE(t, TOUCH_NONE, 4, 4)

    // ---- drain tile t = NT-1 (no staging; vmcnt 2 -> 0)
    {
        const int cb = ((NT - 1) & 1) << 16;
        // P0: read Alo+Blo (proven @prev P3); prove Bhi.
#pragma unroll
        for (int i = 0; i < 4; ++i) { Ar[i][0] = RD_A(cb, ALO, i*2); Ar[i][1] = RD_A(cb, ALO, i*2+1); }
#pragma unroll
        for (int j = 0; j < 2; ++j) { Bl[j][0] = RD_B(cb, BLO, j*2); Bl[j][1] = RD_B(cb, BLO, j*2+1); }
        VMCNT(2);   // outstanding {Bhi, Ahi}=4 -> proves Bhi
        BAR; LGKM0; SCHEDB;
        PRIO1;
#pragma unroll
        for (int i = 0; i < 4; ++i)
#pragma unroll
            for (int j = 0; j < 2; ++j) {
                acc[i][j] = __builtin_amdgcn_mfma_f32_16x16x32_bf16(Ar[i][0], Bl[j][0], acc[i][j], 0, 0, 0);
                acc[i][j] = __builtin_amdgcn_mfma_f32_16x16x32_bf16(Ar[i][1], Bl[j][1], acc[i][j], 0, 0, 0);
            }
        PRIO0; SCHEDB; BAR;
        // P1: read Bhi; prove Ahi.
#pragma unroll
        for (int j = 0; j < 2; ++j) { Bh[j][0] = RD_B(cb, BHI, j*2); Bh[j][1] = RD_B(cb, BHI, j*2+1); }
        VMCNT(0);
        BAR; LGKM0; SCHEDB;
        PRIO1;
#pragma unroll
        for (int i = 0; i < 4; ++i)
#pragma unroll
            for (int j = 0; j < 2; ++j) {
                acc[i][2+j] = __builtin_amdgcn_mfma_f32_16x16x32_bf16(Ar[i][0], Bh[j][0], acc[i][2+j], 0, 0, 0);
                acc[i][2+j] = __builtin_amdgcn_mfma_f32_16x16x32_bf16(Ar[i][1], Bh[j][1], acc[i][2+j], 0, 0, 0);
            }
        PRIO0; SCHEDB; BAR;
        // P2: read Ahi.
#pragma unroll
        for (int i = 0; i < 4; ++i) { Ar[i][0] = RD_A(cb, AHI, i*2); Ar[i][1] = RD_A(cb, AHI, i*2+1); }
        BAR; LGKM0; SCHEDB;
        PRIO1;
#pragma unroll
        for (int i = 0; i < 4; ++i)
#pragma unroll
            for (int j = 0; j < 2; ++j) {
                acc[4+i][2+j] = __builtin_amdgcn_mfma_f32_16x16x32_bf16(Ar[i][0], Bh[j][0], acc[4+i][2+j], 0, 0, 0);
                acc[4+i][2+j] = __builtin_amdgcn_mfma_f32_16x16x32_bf16(Ar[i][1], Bh[j][1], acc[4+i][2+j], 0, 0, 0);
            }
        PRIO0; SCHEDB; BAR;
        // P3: register-only MFMA.
        PRIO1;
#pragma unroll
        for (int i = 0; i < 4; ++i)
#pragma unroll
            for (int j = 0; j < 2; ++j) {
                acc[4+i][j] = __builtin_amdgcn_mfma_f32_16x16x32_bf16(Ar[i][0], Bl[j][0], acc[4+i][j], 0, 0, 0);
                acc[4+i][j] = __builtin_amdgcn_mfma_f32_16x16x32_bf16(Ar[i][1], Bl[j][1], acc[4+i][j], 0, 0, 0);
            }
        PRIO0;
    }

    __syncthreads();   // end of pipeline: safe to alias LDS for epilogue

    // ---- epilogue: transpose each 16x64 i-slice through LDS, then float4 I/O.
    // C/D layout: col = lane&15 (output col), row = (lane>>4)*4 + reg.
    float* Esf = (float*)smem;
    const int q    = lane >> 4;        // 0..3
    const int c16  = lane & 15;
    const int colg = tileN + wc * 64 + c16 * 4;
    const float4 b4 = *(const float4*)&bias[colg];
    const size_t outV = (size_t)B_DIM * H_DIM;

#pragma unroll
    for (int i = 0; i < 8; ++i) {
        float* Es = Esf + (wave * 2 + (i & 1)) * ES_REGION;
        // stage acc slice i (b32 writes, 2 lanes/bank -> conflict-free)
#pragma unroll
        for (int j = 0; j < 4; ++j)
#pragma unroll
            for (int r = 0; r < 4; ++r)
                Es[(q * 4 + r) * ES_STRIDE + j * 16 + c16] = acc[i][j][r];
        // consume: 4 rows x 64 cols per pass, fully coalesced float4
#pragma unroll
        for (int rg = 0; rg < 4; rg++) {
            const int rloc = rg * 4 + q;
            const float4 a4 = *(const float4*)&Es[rloc * ES_STRIDE + c16 * 4];
            const size_t idx = (size_t)(tileM + wrh * 128 + i * 16 + rloc) * H_DIM + colg;
            const float4 u4 = *(const float4*)&u_in[idx];
            const float4 v4 = *(const float4*)&v_in[idx];
            float4 vn, un;
            vn.x = fmaxf(CV_CONST * v4.x + CUV_CONST * u4.x, 0.0f);
            vn.y = fmaxf(CV_CONST * v4.y + CUV_CONST * u4.y, 0.0f);
            vn.z = fmaxf(CV_CONST * v4.z + CUV_CONST * u4.z, 0.0f);
            vn.w = fmaxf(CV_CONST * v4.w + CUV_CONST * u4.w, 0.0f);
            un.x = fmaxf(CU_CONST * u4.x + AU_CONST * (a4.x + b4.x - vn.x), 0.0f);
            un.y = fmaxf(CU_CONST * u4.y + AU_CONST * (a4.y + b4.y - vn.y), 0.0f);
            un.z = fmaxf(CU_CONST * u4.z + AU_CONST * (a4.z + b4.z - vn.z), 0.0f);
            un.w = fmaxf(CU_CONST * u4.w + AU_CONST * (a4.w + b4.w - vn.w), 0.0f);
            *(float4*)&out[idx]        = un;
            *(float4*)&out[outV + idx] = vn;
        }
    }
}

// ---------------------------------------------------------------------------
extern "C" void kernel_launch(void* const* d_in, const int* in_sizes, int n_in,
                              void* d_out, int out_size, void* d_ws, size_t ws_size,
                              hipStream_t stream) {
    const float* x    = (const float*)d_in[0];
    const float* u    = (const float*)d_in[1];
    const float* v    = (const float*)d_in[2];
    const float* win  = (const float*)d_in[3];
    const float* wr   = (const float*)d_in[4];
    const float* bias = (const float*)d_in[5];
    float* out = (float*)d_out;

    unsigned short* Abf = (unsigned short*)d_ws;
    unsigned short* Wbf = Abf + (size_t)B_DIM * K_DIM;

    pack_all<<<N4_TOT / 256, 256, 0, stream>>>(
        (const float4*)x, (const float4*)u, (const float4*)win, (const float4*)wr,
        Abf, Wbf);

    gemm_fused<<<256, 512, 0, stream>>>(Abf, Wbf, u, v, bias, out);
}

// Round 8
// 371.075 us; speedup vs baseline: 1.0391x; 1.0391x over previous
//
#include <hip/hip_runtime.h>
#include <hip/hip_bf16.h>
#include <stdint.h>

// Problem constants (from setup_inputs): B=8192, D_in=1024, H=2048
#define B_DIM 8192
#define D_IN  1024
#define H_DIM 2048
#define K_DIM (D_IN + H_DIM)   // 3072: A = [x | u], Wc = [win | wr]

#define CV_CONST  (1.0f - 1.0f/150.0f)   // (1-ALPHA_V)
#define CUV_CONST (10.0f/150.0f)         // ALPHA_V*M
#define CU_CONST  0.9f                   // (1-ALPHA_U)
#define AU_CONST  0.1f                   // ALPHA_U

typedef __attribute__((ext_vector_type(8))) short short8;   // 8 bf16 = 4 VGPRs
typedef __attribute__((ext_vector_type(4))) float floatx4;

__device__ __forceinline__ unsigned short f2bf(float f) {
    union { float f; unsigned u; } x; x.f = f;
    unsigned r = x.u + 0x7fffu + ((x.u >> 16) & 1u);
    return (unsigned short)(r >> 16);
}

// ---------------------------------------------------------------------------
// Single fused pack: x,u -> Abf[8192][3072]; win,wr -> Wbf[2048][3072], bf16 RNE.
// ---------------------------------------------------------------------------
#define N4_X   ((B_DIM * D_IN)  / 4)   // 2097152
#define N4_U   ((B_DIM * H_DIM) / 4)   // 4194304
#define N4_WIN ((H_DIM * D_IN)  / 4)   //  524288
#define N4_WR  ((H_DIM * H_DIM) / 4)   // 1048576
#define N4_TOT (N4_X + N4_U + N4_WIN + N4_WR)   // 7864320 (= 30720 * 256)

__global__ __launch_bounds__(256)
void pack_all(const float4* __restrict__ x, const float4* __restrict__ u,
              const float4* __restrict__ win, const float4* __restrict__ wr,
              unsigned short* __restrict__ Abf, unsigned short* __restrict__ Wbf) {
    int i = blockIdx.x * 256 + threadIdx.x;
    const float4* src; unsigned short* dst; int shift, mask, coloff;
    if (i < N4_X)                    { src = x;   dst = Abf; shift = 10; mask = 1023; coloff = 0;    }
    else if (i < N4_X + N4_U)        { i -= N4_X; src = u;   dst = Abf; shift = 11; mask = 2047; coloff = D_IN; }
    else if (i < N4_X + N4_U + N4_WIN){ i -= N4_X + N4_U; src = win; dst = Wbf; shift = 10; mask = 1023; coloff = 0; }
    else                             { i -= N4_X + N4_U + N4_WIN; src = wr; dst = Wbf; shift = 11; mask = 2047; coloff = D_IN; }
    int idx = i << 2;
    int r = idx >> shift;
    int c = idx & mask;
    float4 f = src[i];
    ushort4 o;
    o.x = f2bf(f.x); o.y = f2bf(f.y); o.z = f2bf(f.z); o.w = f2bf(f.w);
    *(ushort4*)(dst + (size_t)r * K_DIM + coloff + c) = o;
}

// ---------------------------------------------------------------------------
// R8 = R2 champion skeleton (4-phase proof-ahead, 147.5 µs), with ONE change:
// XCD tile mapping. Old swizzle put the 8 blocks sharing an A panel on 8
// DIFFERENT XCDs -> zero cross-block L2 reuse -> every staged byte came from
// L3 (768 MB over the K-loop ~= 7.7 TB/s, the suspected bottleneck).
// New mapping: each XCD (bid & 7, HW round-robin heuristic) owns a 4x8
// sub-grid (4 tileM x 8 tileN). Blocks on one XCD share A panels 8-way and
// B panels 4-way in their common L2; lockstep K-schedule means co-resident
// blocks request the same 32 KB chunk within a short window -> L2 hits.
// Expected L3->L2 staging traffic: 768 MB -> ~150-400 MB.
// Mapping is bijective -> correctness independent of the XCD heuristic.
// ---------------------------------------------------------------------------
#define GLOAD_LDS16(gp, lp)                                                          \
    __builtin_amdgcn_global_load_lds(                                                \
        (const __attribute__((address_space(1))) unsigned int*)(gp),                 \
        (__attribute__((address_space(3))) unsigned int*)(lp), 16, 0, 0)

#define VMCNT(n)  asm volatile("s_waitcnt vmcnt(" #n ")" ::: "memory")
#define LGKM0     asm volatile("s_waitcnt lgkmcnt(0)" ::: "memory")
#define SCHEDB    __builtin_amdgcn_sched_barrier(0)
#define BAR       __builtin_amdgcn_s_barrier()
#define PRIO1     __builtin_amdgcn_s_setprio(1)
#define PRIO0     __builtin_amdgcn_s_setprio(0)

#define NT (K_DIM / 64)        // 48 K-tiles

// LDS: 2 buffers x 64 KiB. Unit byte offsets within a buffer:
//   A-lo (i-frags 0..3 of both M halves) : 0
//   B-lo (j-frags 0..1 of all wc)        : 16384
//   B-hi (j-frags 2..3 of all wc)        : 32768
//   A-hi (i-frags 4..7 of both M halves) : 49152
// Each unit = 16 slots x 1024 B; slot = one wave-fragment (lane -> lane*16B).
#define ALO 0
#define BLO 16384
#define BHI 32768
#define AHI 49152

// Epilogue scratch (aliases K-loop LDS after final sync)
#define ES_STRIDE 68
#define ES_REGION (16 * ES_STRIDE)          // 1088 floats per region

__global__ __launch_bounds__(512, 2)
void gemm_fused(const unsigned short* __restrict__ A,   // [8192][3072] bf16
                const unsigned short* __restrict__ Wc,  // [2048][3072] bf16
                const float* __restrict__ u_in,         // [8192][2048]
                const float* __restrict__ v_in,         // [8192][2048]
                const float* __restrict__ bias,         // [2048]
                float* __restrict__ out)                // [u_new | v_new]
{
    __shared__ __align__(16) unsigned char smem[131072];

    const int tid  = threadIdx.x;
    const int wave = tid >> 6;       // 0..7
    const int lane = tid & 63;
    const int wrh  = wave >> 2;      // 0..1 : M half (128 rows)
    const int wc   = wave & 3;       // 0..3 : N quarter (64 cols)

    // XCD-local 4x8 tile sub-grid: xcd = bid&7 (round-robin heuristic),
    // ord = bid>>3 in [0,32). tileM = xcd*4 + (ord&3), tileN = ord>>2.
    // -> per XCD: 4 distinct A panels (8-way shared), 8 B panels (4-way shared).
    const int bid   = blockIdx.x;
    const int xcd   = bid & 7;
    const int ord   = bid >> 3;
    const int tileM = ((xcd << 2) + (ord & 3)) << 8;   // 0..31 * 256
    const int tileN = (ord >> 2) << 8;                 // 0..7  * 256

    const int frow = lane & 15;
    const int g    = lane >> 4;

    // Staging source pointers: thread (wave,lane) feeds slot (r*8+wave), lane l.
    const unsigned short* Ag = A  + (size_t)(tileM + (wave >> 1) * 16 + frow) * K_DIM
                                  + (wave & 1) * 32 + g * 8;
    const unsigned short* Bg = Wc + (size_t)(tileN + (wave >> 2) * 64 + ((wave >> 1) & 1) * 16 + frow) * K_DIM
                                  + (wave & 1) * 32 + g * 8;
    const size_t R128 = (size_t)128 * K_DIM;
    const size_t R64  = (size_t) 64 * K_DIM;
    const size_t R32  = (size_t) 32 * K_DIM;

    const int w1024 = wave << 10;

    // ds_read byte bases (within a buffer): A frag (i,s) -> slot wrh*8 + i*2 + s;
    //                                       B frag (j,s) -> slot wc*4 + j*2 + s.
    const int aRd = (wrh << 13) + (lane << 4);
    const int bRd = (wc  << 12) + (lane << 4);

    // ---- prologue: stage tile 0 into buffer 0 (order: Alo, Blo, Bhi, Ahi)
    GLOAD_LDS16(Ag,               smem + ALO + w1024);
    GLOAD_LDS16(Ag + R128,        smem + ALO + 8192 + w1024);
    GLOAD_LDS16(Bg,               smem + BLO + w1024);
    GLOAD_LDS16(Bg + R128,        smem + BLO + 8192 + w1024);
    GLOAD_LDS16(Bg + R32,         smem + BHI + w1024);
    GLOAD_LDS16(Bg + R32 + R128,  smem + BHI + 8192 + w1024);
    GLOAD_LDS16(Ag + R64,         smem + AHI + w1024);
    GLOAD_LDS16(Ag + R64 + R128,  smem + AHI + 8192 + w1024);

    // Prove 0.Alo + 0.Blo landed (all waves), then barrier + fence.
    VMCNT(4);
    BAR;
    LGKM0;

    floatx4 acc[8][4] = {};
    short8 Ar[4][2], Bl[2][2], Bh[2][2];

#define RD_A(cb, unit, i2s) (*(const short8*)(smem + (cb) + (unit) + aRd + (i2s) * 1024))
#define RD_B(cb, unit, j2s) (*(const short8*)(smem + (cb) + (unit) + bRd + (j2s) * 1024))

#pragma clang loop unroll(disable)
    for (int t = 0; t < NT - 1; ++t) {
        const int cb = (t & 1) << 16;
        const int nb = cb ^ 65536;
        const size_t kk = (size_t)(t + 1) * 64;

        // ---- P0: stage next A-lo; read cb.Alo + cb.Blo (proven @prev P3);
        //          prove cb.Bhi for P1.
        GLOAD_LDS16(Ag + kk,        smem + nb + ALO + w1024);
        GLOAD_LDS16(Ag + kk + R128, smem + nb + ALO + 8192 + w1024);
#pragma unroll
        for (int i = 0; i < 4; ++i) { Ar[i][0] = RD_A(cb, ALO, i*2); Ar[i][1] = RD_A(cb, ALO, i*2+1); }
#pragma unroll
        for (int j = 0; j < 2; ++j) { Bl[j][0] = RD_B(cb, BLO, j*2); Bl[j][1] = RD_B(cb, BLO, j*2+1); }
        VMCNT(4);   // outstanding {t.Bhi, t.Ahi, (t+1).Alo}=6 -> proves t.Bhi
        BAR; LGKM0; SCHEDB;
        PRIO1;
#pragma unroll
        for (int i = 0; i < 4; ++i)
#pragma unroll
            for (int j = 0; j < 2; ++j) {
                acc[i][j] = __builtin_amdgcn_mfma_f32_16x16x32_bf16(Ar[i][0], Bl[j][0], acc[i][j], 0, 0, 0);
                acc[i][j] = __builtin_amdgcn_mfma_f32_16x16x32_bf16(Ar[i][1], Bl[j][1], acc[i][j], 0, 0, 0);
            }
        PRIO0; SCHEDB; BAR;

        // ---- P1: stage next B-lo; read cb.Bhi; prove cb.Ahi for P2.
        GLOAD_LDS16(Bg + kk,        smem + nb + BLO + w1024);
        GLOAD_LDS16(Bg + kk + R128, smem + nb + BLO + 8192 + w1024);
#pragma unroll
        for (int j = 0; j < 2; ++j) { Bh[j][0] = RD_B(cb, BHI, j*2); Bh[j][1] = RD_B(cb, BHI, j*2+1); }
        VMCNT(4);   // outstanding {t.Ahi, (t+1).Alo, (t+1).Blo}=6 -> proves t.Ahi
        BAR; LGKM0; SCHEDB;
        PRIO1;
#pragma unroll
        for (int i = 0; i < 4; ++i)
#pragma unroll
            for (int j = 0; j < 2; ++j) {
                acc[i][2+j] = __builtin_amdgcn_mfma_f32_16x16x32_bf16(Ar[i][0], Bh[j][0], acc[i][2+j], 0, 0, 0);
                acc[i][2+j] = __builtin_amdgcn_mfma_f32_16x16x32_bf16(Ar[i][1], Bh[j][1], acc[i][2+j], 0, 0, 0);
            }
        PRIO0; SCHEDB; BAR;

        // ---- P2: stage next B-hi; read cb.Ahi (overwrites Ar); nothing to prove
        //          (P3 reads no LDS).
        GLOAD_LDS16(Bg + kk + R32,        smem + nb + BHI + w1024);
        GLOAD_LDS16(Bg + kk + R32 + R128, smem + nb + BHI + 8192 + w1024);
#pragma unroll
        for (int i = 0; i < 4; ++i) { Ar[i][0] = RD_A(cb, AHI, i*2); Ar[i][1] = RD_A(cb, AHI, i*2+1); }
        BAR; LGKM0; SCHEDB;
        PRIO1;
#pragma unroll
        for (int i = 0; i < 4; ++i)
#pragma unroll
            for (int j = 0; j < 2; ++j) {
                acc[4+i][2+j] = __builtin_amdgcn_mfma_f32_16x16x32_bf16(Ar[i][0], Bh[j][0], acc[4+i][2+j], 0, 0, 0);
                acc[4+i][2+j] = __builtin_amdgcn_mfma_f32_16x16x32_bf16(Ar[i][1], Bh[j][1], acc[4+i][2+j], 0, 0, 0);
            }
        PRIO0; SCHEDB; BAR;

        // ---- P3: stage next A-hi; no reads (Ar=A-hi, Bl kept);
        //          prove (t+1).Alo + (t+1).Blo for next P0.
        GLOAD_LDS16(Ag + kk + R64,        smem + nb + AHI + w1024);
        GLOAD_LDS16(Ag + kk + R64 + R128, smem + nb + AHI + 8192 + w1024);
        VMCNT(4);   // outstanding {(t+1).Alo,Blo,Bhi,Ahi}=8 -> proves Alo,Blo
        BAR; LGKM0; SCHEDB;
        PRIO1;
#pragma unroll
        for (int i = 0; i < 4; ++i)
#pragma unroll
            for (int j = 0; j < 2; ++j) {
                acc[4+i][j] = __builtin_amdgcn_mfma_f32_16x16x32_bf16(Ar[i][0], Bl[j][0], acc[4+i][j], 0, 0, 0);
                acc[4+i][j] = __builtin_amdgcn_mfma_f32_16x16x32_bf16(Ar[i][1], Bl[j][1], acc[4+i][j], 0, 0, 0);
            }
        PRIO0; SCHEDB; BAR;
    }

    // ---- drain tile t = NT-1 (no staging; vmcnt 2 -> 0)
    {
        const int cb = ((NT - 1) & 1) << 16;
        // P0: read Alo+Blo (proven @prev P3); prove Bhi.
#pragma unroll
        for (int i = 0; i < 4; ++i) { Ar[i][0] = RD_A(cb, ALO, i*2); Ar[i][1] = RD_A(cb, ALO, i*2+1); }
#pragma unroll
        for (int j = 0; j < 2; ++j) { Bl[j][0] = RD_B(cb, BLO, j*2); Bl[j][1] = RD_B(cb, BLO, j*2+1); }
        VMCNT(2);   // outstanding {Bhi, Ahi}=4 -> proves Bhi
        BAR; LGKM0; SCHEDB;
        PRIO1;
#pragma unroll
        for (int i = 0; i < 4; ++i)
#pragma unroll
            for (int j = 0; j < 2; ++j) {
                acc[i][j] = __builtin_amdgcn_mfma_f32_16x16x32_bf16(Ar[i][0], Bl[j][0], acc[i][j], 0, 0, 0);
                acc[i][j] = __builtin_amdgcn_mfma_f32_16x16x32_bf16(Ar[i][1], Bl[j][1], acc[i][j], 0, 0, 0);
            }
        PRIO0; SCHEDB; BAR;
        // P1: read Bhi; prove Ahi.
#pragma unroll
        for (int j = 0; j < 2; ++j) { Bh[j][0] = RD_B(cb, BHI, j*2); Bh[j][1] = RD_B(cb, BHI, j*2+1); }
        VMCNT(0);
        BAR; LGKM0; SCHEDB;
        PRIO1;
#pragma unroll
        for (int i = 0; i < 4; ++i)
#pragma unroll
            for (int j = 0; j < 2; ++j) {
                acc[i][2+j] = __builtin_amdgcn_mfma_f32_16x16x32_bf16(Ar[i][0], Bh[j][0], acc[i][2+j], 0, 0, 0);
                acc[i][2+j] = __builtin_amdgcn_mfma_f32_16x16x32_bf16(Ar[i][1], Bh[j][1], acc[i][2+j], 0, 0, 0);
            }
        PRIO0; SCHEDB; BAR;
        // P2: read Ahi.
#pragma unroll
        for (int i = 0; i < 4; ++i) { Ar[i][0] = RD_A(cb, AHI, i*2); Ar[i][1] = RD_A(cb, AHI, i*2+1); }
        BAR; LGKM0; SCHEDB;
        PRIO1;
#pragma unroll
        for (int i = 0; i < 4; ++i)
#pragma unroll
            for (int j = 0; j < 2; ++j) {
                acc[4+i][2+j] = __builtin_amdgcn_mfma_f32_16x16x32_bf16(Ar[i][0], Bh[j][0], acc[4+i][2+j], 0, 0, 0);
                acc[4+i][2+j] = __builtin_amdgcn_mfma_f32_16x16x32_bf16(Ar[i][1], Bh[j][1], acc[4+i][2+j], 0, 0, 0);
            }
        PRIO0; SCHEDB; BAR;
        // P3: register-only MFMA.
        PRIO1;
#pragma unroll
        for (int i = 0; i < 4; ++i)
#pragma unroll
            for (int j = 0; j < 2; ++j) {
                acc[4+i][j] = __builtin_amdgcn_mfma_f32_16x16x32_bf16(Ar[i][0], Bl[j][0], acc[4+i][j], 0, 0, 0);
                acc[4+i][j] = __builtin_amdgcn_mfma_f32_16x16x32_bf16(Ar[i][1], Bl[j][1], acc[4+i][j], 0, 0, 0);
            }
        PRIO0;
    }

    __syncthreads();   // end of pipeline: safe to alias LDS for epilogue

    // ---- epilogue: transpose each 16x64 i-slice through LDS, then float4 I/O.
    // C/D layout: col = lane&15 (output col), row = (lane>>4)*4 + reg.
    float* Esf = (float*)smem;
    const int q    = lane >> 4;        // 0..3
    const int c16  = lane & 15;
    const int colg = tileN + wc * 64 + c16 * 4;
    const float4 b4 = *(const float4*)&bias[colg];
    const size_t outV = (size_t)B_DIM * H_DIM;

#pragma unroll
    for (int i = 0; i < 8; ++i) {
        float* Es = Esf + (wave * 2 + (i & 1)) * ES_REGION;
        // stage acc slice i (b32 writes, 2 lanes/bank -> conflict-free)
#pragma unroll
        for (int j = 0; j < 4; ++j)
#pragma unroll
            for (int r = 0; r < 4; ++r)
                Es[(q * 4 + r) * ES_STRIDE + j * 16 + c16] = acc[i][j][r];
        // consume: 4 rows x 64 cols per pass, fully coalesced float4
#pragma unroll
        for (int rg = 0; rg < 4; rg++) {
            const int rloc = rg * 4 + q;
            const float4 a4 = *(const float4*)&Es[rloc * ES_STRIDE + c16 * 4];
            const size_t idx = (size_t)(tileM + wrh * 128 + i * 16 + rloc) * H_DIM + colg;
            const float4 u4 = *(const float4*)&u_in[idx];
            const float4 v4 = *(const float4*)&v_in[idx];
            float4 vn, un;
            vn.x = fmaxf(CV_CONST * v4.x + CUV_CONST * u4.x, 0.0f);
            vn.y = fmaxf(CV_CONST * v4.y + CUV_CONST * u4.y, 0.0f);
            vn.z = fmaxf(CV_CONST * v4.z + CUV_CONST * u4.z, 0.0f);
            vn.w = fmaxf(CV_CONST * v4.w + CUV_CONST * u4.w, 0.0f);
            un.x = fmaxf(CU_CONST * u4.x + AU_CONST * (a4.x + b4.x - vn.x), 0.0f);
            un.y = fmaxf(CU_CONST * u4.y + AU_CONST * (a4.y + b4.y - vn.y), 0.0f);
            un.z = fmaxf(CU_CONST * u4.z + AU_CONST * (a4.z + b4.z - vn.z), 0.0f);
            un.w = fmaxf(CU_CONST * u4.w + AU_CONST * (a4.w + b4.w - vn.w), 0.0f);
            *(float4*)&out[idx]        = un;
            *(float4*)&out[outV + idx] = vn;
        }
    }
}

// ---------------------------------------------------------------------------
extern "C" void kernel_launch(void* const* d_in, const int* in_sizes, int n_in,
                              void* d_out, int out_size, void* d_ws, size_t ws_size,
                              hipStream_t stream) {
    const float* x    = (const float*)d_in[0];
    const float* u    = (const float*)d_in[1];
    const float* v    = (const float*)d_in[2];
    const float* win  = (const float*)d_in[3];
    const float* wr   = (const float*)d_in[4];
    const float* bias = (const float*)d_in[5];
    float* out = (float*)d_out;

    unsigned short* Abf = (unsigned short*)d_ws;
    unsigned short* Wbf = Abf + (size_t)B_DIM * K_DIM;

    pack_all<<<N4_TOT / 256, 256, 0, stream>>>(
        (const float4*)x, (const float4*)u, (const float4*)win, (const float4*)wr,
        Abf, Wbf);

    gemm_fused<<<256, 512, 0, stream>>>(Abf, Wbf, u, v, bias, out);
}